// Round 1
// baseline (138.471 us; speedup 1.0000x reference)
//
#include <hip/hip_runtime.h>
#include <hip/hip_bf16.h>

#define N_NODES 4096
#define C_IN    1024
#define H_HEADS 4
#define D_HEAD  128
#define C_OUT   512   // H_HEADS * D_HEAD

typedef __attribute__((ext_vector_type(8))) short short8;
typedef __attribute__((ext_vector_type(4))) float f32x4;

__device__ __forceinline__ unsigned short f2bf(float f) {
    unsigned u = __float_as_uint(f);
    u += 0x7FFFu + ((u >> 16) & 1u);   // RNE
    return (unsigned short)(u >> 16);
}

__device__ __forceinline__ float sigv(float s) {
    return 1.f / (1.f + __expf(-s)) - 0.5f;
}

// ---------- kernel 1: W [H][C][D] f32 -> Wt [H][D][C] bf16 (transposed for GEMM staging)
__global__ void k_wt(const float* __restrict__ W, unsigned short* __restrict__ Wt) {
    int g = blockIdx.x * blockDim.x + threadIdx.x;   // 131072 threads, 4 elems each
    int o = g * 4;                                   // o = (h*128+d)*1024 + c
    int c  = o & 1023;
    int hd = o >> 10;
    int d  = hd & 127;
    int h  = hd >> 7;
    const float* src = W + (size_t)h * C_IN * D_HEAD + (size_t)c * D_HEAD + d;
    ushort4 p;
    p.x = f2bf(src[0 * D_HEAD]);
    p.y = f2bf(src[1 * D_HEAD]);
    p.z = f2bf(src[2 * D_HEAD]);
    p.w = f2bf(src[3 * D_HEAD]);
    *(ushort4*)(Wt + o) = p;
}

// ---------- kernel 2: Hbuf[N][512] = X @ W per head + b   (bf16 MFMA, f32 out)
#define BM 128
#define BN 64
#define BK 32
#define LDSA_STRIDE 48   // bf16 units (96 B rows, 16B-aligned)
#define LDSB_STRIDE 48

__global__ void k_gemm(const float* __restrict__ X, const unsigned short* __restrict__ Wt,
                       const float* __restrict__ bias, float* __restrict__ Hbuf) {
    __shared__ __align__(16) unsigned short ldsA[BM * LDSA_STRIDE];
    __shared__ __align__(16) unsigned short ldsB[BN * LDSB_STRIDE];
    const int t    = threadIdx.x;
    const int lane = t & 63;
    const int wid  = t >> 6;
    const int wrow = wid >> 1, wcol = wid & 1;
    const int rowStart = blockIdx.y * BM;
    const int colStart = blockIdx.x * BN;
    const int head  = colStart >> 7;
    const int dcol0 = colStart & 127;

    f32x4 acc[4][2];
#pragma unroll
    for (int m = 0; m < 4; ++m)
#pragma unroll
        for (int n = 0; n < 2; ++n) acc[m][n] = (f32x4){0.f, 0.f, 0.f, 0.f};

    const int aq = t & 7;    // k-quad for A
    const int ar = t >> 3;   // 0..31
    const int bq = t & 7;    // k-quad for B
    const int bd = t >> 3;   // 0..31

    for (int k0 = 0; k0 < C_IN; k0 += BK) {
        // stage A: 128 rows x 32 k (f32 -> bf16)
#pragma unroll
        for (int rr = 0; rr < 4; ++rr) {
            int r = ar + rr * 32;
            float4 v = *(const float4*)(X + (size_t)(rowStart + r) * C_IN + k0 + aq * 4);
            ushort4 p;
            p.x = f2bf(v.x); p.y = f2bf(v.y); p.z = f2bf(v.z); p.w = f2bf(v.w);
            *(ushort4*)(ldsA + r * LDSA_STRIDE + aq * 4) = p;
        }
        // stage B: 64 d-rows x 32 k from pre-transposed bf16 Wt
#pragma unroll
        for (int rr = 0; rr < 2; ++rr) {
            int d = bd + rr * 32;
            const unsigned short* src =
                Wt + (size_t)(head * D_HEAD + dcol0 + d) * C_IN + k0 + bq * 4;
            *(ushort4*)(ldsB + d * LDSB_STRIDE + bq * 4) = *(const ushort4*)src;
        }
        __syncthreads();

        const int koff = (lane >> 4) * 8;
        short8 bfr[2];
#pragma unroll
        for (int n = 0; n < 2; ++n) {
            int col = wcol * 32 + n * 16 + (lane & 15);
            bfr[n] = *(const short8*)(ldsB + col * LDSB_STRIDE + koff);
        }
#pragma unroll
        for (int m = 0; m < 4; ++m) {
            int row = wrow * 64 + m * 16 + (lane & 15);
            short8 a = *(const short8*)(ldsA + row * LDSA_STRIDE + koff);
#pragma unroll
            for (int n = 0; n < 2; ++n)
                acc[m][n] = __builtin_amdgcn_mfma_f32_16x16x32_bf16(a, bfr[n], acc[m][n], 0, 0, 0);
        }
        __syncthreads();
    }

    // epilogue: C layout col=lane&15, row=(lane>>4)*4+r   [m89/m91]
#pragma unroll
    for (int m = 0; m < 4; ++m) {
        int row_g = rowStart + wrow * 64 + m * 16 + (lane >> 4) * 4;
#pragma unroll
        for (int n = 0; n < 2; ++n) {
            int col_g = colStart + wcol * 32 + n * 16 + (lane & 15);
            float bb = bias[col_g];
#pragma unroll
            for (int r = 0; r < 4; ++r)
                Hbuf[(size_t)(row_g + r) * C_OUT + col_g] = acc[m][n][r] + bb;
        }
    }
}

// ---------- kernel 3: F1[n][h], F2[n][h]
__global__ void k_f12(const float* __restrict__ Hbuf, const float* __restrict__ v0,
                      const float* __restrict__ v1, float* __restrict__ F1,
                      float* __restrict__ F2) {
    int n = blockIdx.x;
    int t = threadIdx.x;
    int head = t >> 6, lane = t & 63;
    const float* hrow = Hbuf + (size_t)n * C_OUT + head * D_HEAD;
    float h0 = hrow[lane], h1 = hrow[lane + 64];
    const float* v0h = v0 + head * D_HEAD;
    const float* v1h = v1 + head * D_HEAD;
    float s1 = h0 * v0h[lane] + h1 * v0h[lane + 64];
    float s2 = h0 * v1h[lane] + h1 * v1h[lane + 64];
#pragma unroll
    for (int off = 32; off; off >>= 1) {
        s1 += __shfl_xor(s1, off);
        s2 += __shfl_xor(s2, off);
    }
    if (lane == 0) {
        F1[n * 4 + head] = s1;
        F2[n * 4 + head] = s2;
    }
}

// ---------- kernel 4: per-row sparse softmax + PV
__global__ void k_attn(const float* __restrict__ adj, const float* __restrict__ Hbuf,
                       const float* __restrict__ F1, const float* __restrict__ F2,
                       float* __restrict__ Out) {
    __shared__ int   idxs[N_NODES];   // 16 KB worst-case-proof
    __shared__ float evals[1024];     // 256 entries x 4 heads
    __shared__ int   wtot[4];
    __shared__ float red[16];

    const int i    = blockIdx.x;
    const int t    = threadIdx.x;
    const int lane = t & 63;
    const int wid  = t >> 6;
    const int head = t >> 6;   // thread owns cols 2t,2t+1 -> head = t>>6

    float4 f1v = *(const float4*)(F1 + i * 4);

    // ---- deterministic compaction of nonzero columns
    const float4* arow = (const float4*)(adj + (size_t)i * N_NODES);
    float4 av[4];
    int cnt = 0;
#pragma unroll
    for (int r = 0; r < 4; ++r) {
        av[r] = arow[r * 256 + t];
        cnt += (av[r].x != 0.f) + (av[r].y != 0.f) + (av[r].z != 0.f) + (av[r].w != 0.f);
    }
    int v = cnt;
#pragma unroll
    for (int off = 1; off < 64; off <<= 1) {
        int u = __shfl_up(v, off);
        if (lane >= off) v += u;
    }
    if (lane == 63) wtot[wid] = v;
    __syncthreads();
    int wpre = 0, nnz = 0;
#pragma unroll
    for (int w = 0; w < 4; ++w) {
        int tw = wtot[w];
        if (w < wid) wpre += tw;
        nnz += tw;
    }
    int off = wpre + v - cnt;
#pragma unroll
    for (int r = 0; r < 4; ++r) {
        int j0 = (r * 256 + t) * 4;
        if (av[r].x != 0.f) idxs[off++] = j0;
        if (av[r].y != 0.f) idxs[off++] = j0 + 1;
        if (av[r].z != 0.f) idxs[off++] = j0 + 2;
        if (av[r].w != 0.f) idxs[off++] = j0 + 3;
    }
    __syncthreads();

    // ---- phase 2: per-head row max over live entries
    float mx[4] = {-1e30f, -1e30f, -1e30f, -1e30f};
    for (int jj = t; jj < nnz; jj += 256) {
        int j = idxs[jj];
        float4 f2v = *(const float4*)(F2 + j * 4);
        float s0 = f1v.x + f2v.x, s1 = f1v.y + f2v.y;
        float s2 = f1v.z + f2v.z, s3 = f1v.w + f2v.w;
        if (s0 != 0.f) mx[0] = fmaxf(mx[0], sigv(s0));
        if (s1 != 0.f) mx[1] = fmaxf(mx[1], sigv(s1));
        if (s2 != 0.f) mx[2] = fmaxf(mx[2], sigv(s2));
        if (s3 != 0.f) mx[3] = fmaxf(mx[3], sigv(s3));
    }
#pragma unroll
    for (int h = 0; h < 4; ++h)
#pragma unroll
        for (int o2 = 32; o2; o2 >>= 1) mx[h] = fmaxf(mx[h], __shfl_xor(mx[h], o2));
    if (lane == 0) {
        red[wid * 4 + 0] = mx[0]; red[wid * 4 + 1] = mx[1];
        red[wid * 4 + 2] = mx[2]; red[wid * 4 + 3] = mx[3];
    }
    __syncthreads();
    float rowmax[4];
#pragma unroll
    for (int h = 0; h < 4; ++h)
        rowmax[h] = fmaxf(fmaxf(red[0 + h], red[4 + h]), fmaxf(red[8 + h], red[12 + h]));
    __syncthreads();   // red reused below

    // ---- phase 3: exp + denom + PV, chunks of 256 entries
    float2 acc = {0.f, 0.f};
    float dpart[4] = {0.f, 0.f, 0.f, 0.f};
    const float2* __restrict__ H2 = (const float2*)Hbuf;
    for (int base = 0; base < nnz; base += 256) {
        int m = min(256, nnz - base);
        if (t < m) {
            int j = idxs[base + t];
            float4 f2v = *(const float4*)(F2 + j * 4);
            float s0 = f1v.x + f2v.x, s1 = f1v.y + f2v.y;
            float s2 = f1v.z + f2v.z, s3 = f1v.w + f2v.w;
            float e0 = (s0 != 0.f) ? __expf(sigv(s0) - rowmax[0]) : 0.f;
            float e1 = (s1 != 0.f) ? __expf(sigv(s1) - rowmax[1]) : 0.f;
            float e2 = (s2 != 0.f) ? __expf(sigv(s2) - rowmax[2]) : 0.f;
            float e3 = (s3 != 0.f) ? __expf(sigv(s3) - rowmax[3]) : 0.f;
            evals[t * 4 + 0] = e0; evals[t * 4 + 1] = e1;
            evals[t * 4 + 2] = e2; evals[t * 4 + 3] = e3;
            dpart[0] += e0; dpart[1] += e1; dpart[2] += e2; dpart[3] += e3;
        }
        __syncthreads();
        for (int jj = 0; jj < m; ++jj) {
            int j = idxs[base + jj];
            float e = evals[jj * 4 + head];
            float2 hv = H2[(size_t)j * 256 + t];
            acc.x += e * hv.x;
            acc.y += e * hv.y;
        }
        __syncthreads();
    }

    // ---- denom reduce + write
#pragma unroll
    for (int h = 0; h < 4; ++h)
#pragma unroll
        for (int o2 = 32; o2; o2 >>= 1) dpart[h] += __shfl_xor(dpart[h], o2);
    if (lane == 0) {
        red[wid * 4 + 0] = dpart[0]; red[wid * 4 + 1] = dpart[1];
        red[wid * 4 + 2] = dpart[2]; red[wid * 4 + 3] = dpart[3];
    }
    __syncthreads();
    float dn = red[0 + head] + red[4 + head] + red[8 + head] + red[12 + head];
    float2 o;
    if (dn > 0.f) {
        float inv = 1.f / fmaxf(dn, 1e-30f);
        o.x = acc.x * inv;
        o.y = acc.y * inv;
    } else {
        o.x = 0.f; o.y = 0.f;
    }
    *(float2*)(Out + (size_t)i * C_OUT + 2 * t) = o;
}

// ---------- launch
extern "C" void kernel_launch(void* const* d_in, const int* in_sizes, int n_in,
                              void* d_out, int out_size, void* d_ws, size_t ws_size,
                              hipStream_t stream) {
    const float* X   = (const float*)d_in[0];
    const float* adj = (const float*)d_in[1];
    const float* W   = (const float*)d_in[2];
    const float* b   = (const float*)d_in[3];
    const float* v0  = (const float*)d_in[4];
    const float* v1  = (const float*)d_in[5];
    float* out = (float*)d_out;

    char* ws = (char*)d_ws;
    float*          Hbuf = (float*)ws;                                     // 8 MB
    unsigned short* Wt   = (unsigned short*)(ws + (size_t)N_NODES * C_OUT * 4); // 1 MB
    float*          F1   = (float*)(ws + (size_t)9 * 1024 * 1024);         // 64 KB
    float*          F2   = F1 + N_NODES * 4;                               // 64 KB

    k_wt<<<512, 256, 0, stream>>>(W, Wt);
    dim3 ggrid(C_OUT / BN, N_NODES / BM);
    k_gemm<<<ggrid, 256, 0, stream>>>(X, Wt, b, Hbuf);
    k_f12<<<N_NODES, 256, 0, stream>>>(Hbuf, v0, v1, F1, F2);
    k_attn<<<N_NODES, 256, 0, stream>>>(adj, Hbuf, F1, F2, out);
}

// Round 2
// 103.616 us; speedup vs baseline: 1.3364x; 1.3364x over previous
//
#include <hip/hip_runtime.h>
#include <hip/hip_bf16.h>

#define N_NODES 4096
#define C_IN    1024
#define H_HEADS 4
#define D_HEAD  128
#define C_OUT   512   // H_HEADS * D_HEAD

typedef __attribute__((ext_vector_type(8))) short short8;
typedef __attribute__((ext_vector_type(4))) float f32x4;

__device__ __forceinline__ unsigned short f2bf(float f) {
    unsigned u = __float_as_uint(f);
    u += 0x7FFFu + ((u >> 16) & 1u);   // RNE
    return (unsigned short)(u >> 16);
}

__device__ __forceinline__ float sigv(float s) {
    return 1.f / (1.f + __expf(-s)) - 0.5f;
}

#define GLOAD_LDS16(gp, lp)                                                        \
    __builtin_amdgcn_global_load_lds(                                              \
        (const __attribute__((address_space(1))) unsigned int*)(gp),               \
        (__attribute__((address_space(3))) unsigned int*)(lp), 16, 0, 0)

// ---------- kernel 0: X [N][C_IN] f32 -> bf16
__global__ void k_xb(const float* __restrict__ X, unsigned short* __restrict__ Xb) {
    int g = blockIdx.x * blockDim.x + threadIdx.x;   // each thread: 8 elems
    const float4* s = (const float4*)(X + (size_t)g * 8);
    float4 a = s[0], b = s[1];
    ushort4 p0, p1;
    p0.x = f2bf(a.x); p0.y = f2bf(a.y); p0.z = f2bf(a.z); p0.w = f2bf(a.w);
    p1.x = f2bf(b.x); p1.y = f2bf(b.y); p1.z = f2bf(b.z); p1.w = f2bf(b.w);
    ushort4* d = (ushort4*)(Xb + (size_t)g * 8);
    d[0] = p0; d[1] = p1;
}

// ---------- kernel 1: W [H][C][D] f32 -> Wt [(h*D+d)][C] bf16 (B^T layout)
__global__ void k_wt(const float* __restrict__ W, unsigned short* __restrict__ Wt) {
    int g = blockIdx.x * blockDim.x + threadIdx.x;
    int o = g * 4;                                   // o = (h*128+d)*1024 + c
    int c  = o & 1023;
    int hd = o >> 10;
    int d  = hd & 127;
    int h  = hd >> 7;
    const float* src = W + (size_t)h * C_IN * D_HEAD + (size_t)c * D_HEAD + d;
    ushort4 p;
    p.x = f2bf(src[0 * D_HEAD]);
    p.y = f2bf(src[1 * D_HEAD]);
    p.z = f2bf(src[2 * D_HEAD]);
    p.w = f2bf(src[3 * D_HEAD]);
    *(ushort4*)(Wt + o) = p;
}

// ---------- kernel 2: Hbuf[N][512] = Xb @ Wt^T + b   (m97-style bf16 MFMA)
// BM=128, BN=64, BK=64 (two 32-k halves), 4 waves (2x2), global_load_lds w16.
__global__ void k_gemm(const unsigned short* __restrict__ Xb,
                       const unsigned short* __restrict__ Wt,
                       const float* __restrict__ bias, float* __restrict__ Hbuf) {
    __shared__ __align__(16) unsigned short ldsA[2 * 128 * 32];   // 16 KB
    __shared__ __align__(16) unsigned short ldsB[2 * 64 * 32];    //  8 KB
    const int t    = threadIdx.x;
    const int lane = t & 63;
    const int wid  = t >> 6;
    const int wrow = wid >> 1, wcol = wid & 1;
    const int rowStart = blockIdx.y * 128;
    const int colStart = blockIdx.x * 64;

    f32x4 acc[4][2];
#pragma unroll
    for (int m = 0; m < 4; ++m)
#pragma unroll
        for (int n = 0; n < 2; ++n) acc[m][n] = (f32x4){0.f, 0.f, 0.f, 0.f};

    const int lrow = lane >> 2;   // 0..15  (row within 16-row chunk)
    const int lkq  = lane & 3;    // 0..3   (16-B k-quad within 32-k half)

    for (int k0 = 0; k0 < C_IN; k0 += 64) {
        // --- stage A: 16 chunks of 1024 B, 4 per wave
#pragma unroll
        for (int i = 0; i < 4; ++i) {
            int c  = wid * 4 + i;          // wave-uniform
            int h  = c >> 3, rb = c & 7;
            const unsigned short* g =
                Xb + (size_t)(rowStart + rb * 16 + lrow) * C_IN + k0 + h * 32 + lkq * 8;
            GLOAD_LDS16(g, ldsA + h * 4096 + rb * 512);
        }
        // --- stage B: 8 chunks of 1024 B, 2 per wave
#pragma unroll
        for (int i = 0; i < 2; ++i) {
            int c  = wid * 2 + i;          // wave-uniform
            int h  = c >> 2, db = c & 3;
            const unsigned short* g =
                Wt + (size_t)(colStart + db * 16 + lrow) * C_IN + k0 + h * 32 + lkq * 8;
            GLOAD_LDS16(g, ldsB + h * 2048 + db * 512);
        }
        __syncthreads();

        const int fo = (lane >> 4) * 8;    // k-offset within 32-k half
        const int fr = lane & 15;
#pragma unroll
        for (int h = 0; h < 2; ++h) {
            short8 bfr[2];
#pragma unroll
            for (int n = 0; n < 2; ++n)
                bfr[n] = *(const short8*)(ldsB + h * 2048 + (wcol * 32 + n * 16 + fr) * 32 + fo);
#pragma unroll
            for (int m = 0; m < 4; ++m) {
                short8 a = *(const short8*)(ldsA + h * 4096 + (wrow * 64 + m * 16 + fr) * 32 + fo);
#pragma unroll
                for (int n = 0; n < 2; ++n)
                    acc[m][n] = __builtin_amdgcn_mfma_f32_16x16x32_bf16(a, bfr[n], acc[m][n], 0, 0, 0);
            }
        }
        __syncthreads();
    }

    // epilogue: C layout col=lane&15, row=(lane>>4)*4+r   [m89/m91]
#pragma unroll
    for (int m = 0; m < 4; ++m) {
        int row_g = rowStart + wrow * 64 + m * 16 + (lane >> 4) * 4;
#pragma unroll
        for (int n = 0; n < 2; ++n) {
            int col_g = colStart + wcol * 32 + n * 16 + (lane & 15);
            float bb = bias[col_g];
#pragma unroll
            for (int r = 0; r < 4; ++r)
                Hbuf[(size_t)(row_g + r) * C_OUT + col_g] = acc[m][n][r] + bb;
        }
    }
}

// ---------- kernel 3: F1[n][h], F2[n][h]
__global__ void k_f12(const float* __restrict__ Hbuf, const float* __restrict__ v0,
                      const float* __restrict__ v1, float* __restrict__ F1,
                      float* __restrict__ F2) {
    int n = blockIdx.x;
    int t = threadIdx.x;
    int head = t >> 6, lane = t & 63;
    const float* hrow = Hbuf + (size_t)n * C_OUT + head * D_HEAD;
    float h0 = hrow[lane], h1 = hrow[lane + 64];
    const float* v0h = v0 + head * D_HEAD;
    const float* v1h = v1 + head * D_HEAD;
    float s1 = h0 * v0h[lane] + h1 * v0h[lane + 64];
    float s2 = h0 * v1h[lane] + h1 * v1h[lane + 64];
#pragma unroll
    for (int off = 32; off; off >>= 1) {
        s1 += __shfl_xor(s1, off);
        s2 += __shfl_xor(s2, off);
    }
    if (lane == 0) {
        F1[n * 4 + head] = s1;
        F2[n * 4 + head] = s2;
    }
}

// ---------- kernel 4: per-row sparse softmax + PV
__global__ void k_attn(const float* __restrict__ adj, const float* __restrict__ Hbuf,
                       const float* __restrict__ F1, const float* __restrict__ F2,
                       float* __restrict__ Out) {
    __shared__ int   idxs[N_NODES];   // 16 KB worst-case-proof
    __shared__ float evals[1024];     // 256 entries x 4 heads
    __shared__ int   wtot[4];
    __shared__ float red[16];

    const int i    = blockIdx.x;
    const int t    = threadIdx.x;
    const int lane = t & 63;
    const int wid  = t >> 6;
    const int head = t >> 6;   // thread owns cols 2t,2t+1 -> head = t>>6

    float4 f1v = *(const float4*)(F1 + i * 4);

    // ---- deterministic compaction of nonzero columns
    const float4* arow = (const float4*)(adj + (size_t)i * N_NODES);
    float4 av[4];
    int cnt = 0;
#pragma unroll
    for (int r = 0; r < 4; ++r) {
        av[r] = arow[r * 256 + t];
        cnt += (av[r].x != 0.f) + (av[r].y != 0.f) + (av[r].z != 0.f) + (av[r].w != 0.f);
    }
    int v = cnt;
#pragma unroll
    for (int off = 1; off < 64; off <<= 1) {
        int u = __shfl_up(v, off);
        if (lane >= off) v += u;
    }
    if (lane == 63) wtot[wid] = v;
    __syncthreads();
    int wpre = 0, nnz = 0;
#pragma unroll
    for (int w = 0; w < 4; ++w) {
        int tw = wtot[w];
        if (w < wid) wpre += tw;
        nnz += tw;
    }
    int off = wpre + v - cnt;
#pragma unroll
    for (int r = 0; r < 4; ++r) {
        int j0 = (r * 256 + t) * 4;
        if (av[r].x != 0.f) idxs[off++] = j0;
        if (av[r].y != 0.f) idxs[off++] = j0 + 1;
        if (av[r].z != 0.f) idxs[off++] = j0 + 2;
        if (av[r].w != 0.f) idxs[off++] = j0 + 3;
    }
    __syncthreads();

    // ---- phase 2: per-head row max over live entries
    float mx[4] = {-1e30f, -1e30f, -1e30f, -1e30f};
    for (int jj = t; jj < nnz; jj += 256) {
        int j = idxs[jj];
        float4 f2v = *(const float4*)(F2 + j * 4);
        float s0 = f1v.x + f2v.x, s1 = f1v.y + f2v.y;
        float s2 = f1v.z + f2v.z, s3 = f1v.w + f2v.w;
        if (s0 != 0.f) mx[0] = fmaxf(mx[0], sigv(s0));
        if (s1 != 0.f) mx[1] = fmaxf(mx[1], sigv(s1));
        if (s2 != 0.f) mx[2] = fmaxf(mx[2], sigv(s2));
        if (s3 != 0.f) mx[3] = fmaxf(mx[3], sigv(s3));
    }
#pragma unroll
    for (int h = 0; h < 4; ++h)
#pragma unroll
        for (int o2 = 32; o2; o2 >>= 1) mx[h] = fmaxf(mx[h], __shfl_xor(mx[h], o2));
    if (lane == 0) {
        red[wid * 4 + 0] = mx[0]; red[wid * 4 + 1] = mx[1];
        red[wid * 4 + 2] = mx[2]; red[wid * 4 + 3] = mx[3];
    }
    __syncthreads();
    float rowmax[4];
#pragma unroll
    for (int h = 0; h < 4; ++h)
        rowmax[h] = fmaxf(fmaxf(red[0 + h], red[4 + h]), fmaxf(red[8 + h], red[12 + h]));
    __syncthreads();   // red reused below

    // ---- phase 3: exp + denom + PV, chunks of 256 entries
    float2 acc = {0.f, 0.f};
    float dpart[4] = {0.f, 0.f, 0.f, 0.f};
    const float2* __restrict__ H2 = (const float2*)Hbuf;
    for (int base = 0; base < nnz; base += 256) {
        int m = min(256, nnz - base);
        if (t < m) {
            int j = idxs[base + t];
            float4 f2v = *(const float4*)(F2 + j * 4);
            float s0 = f1v.x + f2v.x, s1 = f1v.y + f2v.y;
            float s2 = f1v.z + f2v.z, s3 = f1v.w + f2v.w;
            float e0 = (s0 != 0.f) ? __expf(sigv(s0) - rowmax[0]) : 0.f;
            float e1 = (s1 != 0.f) ? __expf(sigv(s1) - rowmax[1]) : 0.f;
            float e2 = (s2 != 0.f) ? __expf(sigv(s2) - rowmax[2]) : 0.f;
            float e3 = (s3 != 0.f) ? __expf(sigv(s3) - rowmax[3]) : 0.f;
            evals[t * 4 + 0] = e0; evals[t * 4 + 1] = e1;
            evals[t * 4 + 2] = e2; evals[t * 4 + 3] = e3;
            dpart[0] += e0; dpart[1] += e1; dpart[2] += e2; dpart[3] += e3;
        }
        __syncthreads();
        for (int jj = 0; jj < m; ++jj) {
            int j = idxs[base + jj];
            float e = evals[jj * 4 + head];
            float2 hv = H2[(size_t)j * 256 + t];
            acc.x += e * hv.x;
            acc.y += e * hv.y;
        }
        __syncthreads();
    }

    // ---- denom reduce + write
#pragma unroll
    for (int h = 0; h < 4; ++h)
#pragma unroll
        for (int o2 = 32; o2; o2 >>= 1) dpart[h] += __shfl_xor(dpart[h], o2);
    if (lane == 0) {
        red[wid * 4 + 0] = dpart[0]; red[wid * 4 + 1] = dpart[1];
        red[wid * 4 + 2] = dpart[2]; red[wid * 4 + 3] = dpart[3];
    }
    __syncthreads();
    float dn = red[0 + head] + red[4 + head] + red[8 + head] + red[12 + head];
    float2 o;
    if (dn > 0.f) {
        float inv = 1.f / fmaxf(dn, 1e-30f);
        o.x = acc.x * inv;
        o.y = acc.y * inv;
    } else {
        o.x = 0.f; o.y = 0.f;
    }
    *(float2*)(Out + (size_t)i * C_OUT + 2 * t) = o;
}

// ---------- launch
extern "C" void kernel_launch(void* const* d_in, const int* in_sizes, int n_in,
                              void* d_out, int out_size, void* d_ws, size_t ws_size,
                              hipStream_t stream) {
    const float* X   = (const float*)d_in[0];
    const float* adj = (const float*)d_in[1];
    const float* W   = (const float*)d_in[2];
    const float* b   = (const float*)d_in[3];
    const float* v0  = (const float*)d_in[4];
    const float* v1  = (const float*)d_in[5];
    float* out = (float*)d_out;

    char* ws = (char*)d_ws;
    float*          Hbuf = (float*)ws;                                          // 8 MB
    unsigned short* Wt   = (unsigned short*)(ws + (size_t)N_NODES * C_OUT * 4); // 1 MB
    unsigned short* Xb   = (unsigned short*)(ws + (size_t)9 * 1024 * 1024);     // 8 MB
    float*          F1   = (float*)(ws + (size_t)17 * 1024 * 1024);             // 64 KB
    float*          F2   = F1 + N_NODES * 4;                                    // 64 KB

    k_xb<<<2048, 256, 0, stream>>>(X, Xb);
    k_wt<<<512, 256, 0, stream>>>(W, Wt);
    dim3 ggrid(C_OUT / 64, N_NODES / 128);
    k_gemm<<<ggrid, 256, 0, stream>>>(Xb, Wt, b, Hbuf);
    k_f12<<<N_NODES, 256, 0, stream>>>(Hbuf, v0, v1, F1, F2);
    k_attn<<<N_NODES, 256, 0, stream>>>(adj, Hbuf, F1, F2, out);
}

// Round 3
// 75.288 us; speedup vs baseline: 1.8392x; 1.3763x over previous
//
#include <hip/hip_runtime.h>
#include <hip/hip_bf16.h>

#define N_NODES 4096
#define C_IN    1024
#define H_HEADS 4
#define D_HEAD  128
#define C_OUT   512   // H_HEADS * D_HEAD

typedef __attribute__((ext_vector_type(8))) short short8;
typedef __attribute__((ext_vector_type(8))) unsigned short u16x8;
typedef __attribute__((ext_vector_type(4))) float f32x4;

__device__ __forceinline__ unsigned short f2bf(float f) {
    unsigned u = __float_as_uint(f);
    u += 0x7FFFu + ((u >> 16) & 1u);   // RNE
    return (unsigned short)(u >> 16);
}
__device__ __forceinline__ float bf2f(unsigned short u) {
    return __uint_as_float((unsigned)u << 16);
}
__device__ __forceinline__ float sigv(float s) {
    return 1.f / (1.f + __expf(-s)) - 0.5f;
}

#define GLOAD_LDS16(gp, lp)                                                        \
    __builtin_amdgcn_global_load_lds(                                              \
        (const __attribute__((address_space(1))) unsigned int*)(gp),               \
        (__attribute__((address_space(3))) unsigned int*)(lp), 16, 0, 0)

// ---------- kernel 0: X [N][C_IN] f32 -> bf16
__global__ void k_xb(const float* __restrict__ X, unsigned short* __restrict__ Xb) {
    int g = blockIdx.x * blockDim.x + threadIdx.x;   // each thread: 8 elems
    const float4* s = (const float4*)(X + (size_t)g * 8);
    float4 a = s[0], b = s[1];
    ushort4 p0, p1;
    p0.x = f2bf(a.x); p0.y = f2bf(a.y); p0.z = f2bf(a.z); p0.w = f2bf(a.w);
    p1.x = f2bf(b.x); p1.y = f2bf(b.y); p1.z = f2bf(b.z); p1.w = f2bf(b.w);
    ushort4* d = (ushort4*)(Xb + (size_t)g * 8);
    d[0] = p0; d[1] = p1;
}

// ---------- kernel 1: W [H][C][D] f32 -> Wt [(h*D+d)][C] bf16 (B^T layout)
__global__ void k_wt(const float* __restrict__ W, unsigned short* __restrict__ Wt) {
    int g = blockIdx.x * blockDim.x + threadIdx.x;
    int o = g * 4;                                   // o = (h*128+d)*1024 + c
    int c  = o & 1023;
    int hd = o >> 10;
    int d  = hd & 127;
    int h  = hd >> 7;
    const float* src = W + (size_t)h * C_IN * D_HEAD + (size_t)c * D_HEAD + d;
    ushort4 p;
    p.x = f2bf(src[0 * D_HEAD]);
    p.y = f2bf(src[1 * D_HEAD]);
    p.z = f2bf(src[2 * D_HEAD]);
    p.w = f2bf(src[3 * D_HEAD]);
    *(ushort4*)(Wt + o) = p;
}

// ---------- kernel 2: Hbuf[N][512] = Xb @ Wt^T + b   (m97-style bf16 MFMA)
// BM=128, BN=64, BK=64 (two 32-k halves), 4 waves (2x2), global_load_lds w16.
// 1-D grid of 256 with XCD-aware swizzle: XCD k gets rows 4k..4k+3 x all cols.
__global__ void k_gemm(const unsigned short* __restrict__ Xb,
                       const unsigned short* __restrict__ Wt,
                       const float* __restrict__ bias, float* __restrict__ Hbuf) {
    __shared__ __align__(16) unsigned short ldsA[2 * 128 * 32];   // 16 KB
    __shared__ __align__(16) unsigned short ldsB[2 * 64 * 32];    //  8 KB
    const int t    = threadIdx.x;
    const int lane = t & 63;
    const int wid  = t >> 6;
    const int wrow = wid >> 1, wcol = wid & 1;
    const int bid  = blockIdx.x;
    const int lin  = (bid & 7) * 32 + (bid >> 3);   // bijective XCD swizzle (256 = 8*32)
    const int rowStart = (lin >> 3) * 128;
    const int colStart = (lin & 7) * 64;

    f32x4 acc[4][2];
#pragma unroll
    for (int m = 0; m < 4; ++m)
#pragma unroll
        for (int n = 0; n < 2; ++n) acc[m][n] = (f32x4){0.f, 0.f, 0.f, 0.f};

    const int lrow = lane >> 2;   // 0..15  (row within 16-row chunk)
    const int lkq  = lane & 3;    // 0..3   (16-B k-quad within 32-k half)

    for (int k0 = 0; k0 < C_IN; k0 += 64) {
        // --- stage A: 16 chunks of 1024 B, 4 per wave
#pragma unroll
        for (int i = 0; i < 4; ++i) {
            int c  = wid * 4 + i;          // wave-uniform
            int h  = c >> 3, rb = c & 7;
            const unsigned short* g =
                Xb + (size_t)(rowStart + rb * 16 + lrow) * C_IN + k0 + h * 32 + lkq * 8;
            GLOAD_LDS16(g, ldsA + h * 4096 + rb * 512);
        }
        // --- stage B: 8 chunks of 1024 B, 2 per wave
#pragma unroll
        for (int i = 0; i < 2; ++i) {
            int c  = wid * 2 + i;          // wave-uniform
            int h  = c >> 2, db = c & 3;
            const unsigned short* g =
                Wt + (size_t)(colStart + db * 16 + lrow) * C_IN + k0 + h * 32 + lkq * 8;
            GLOAD_LDS16(g, ldsB + h * 2048 + db * 512);
        }
        __syncthreads();

        const int fo = (lane >> 4) * 8;    // k-offset within 32-k half
        const int fr = lane & 15;
#pragma unroll
        for (int h = 0; h < 2; ++h) {
            short8 bfr[2];
#pragma unroll
            for (int n = 0; n < 2; ++n)
                bfr[n] = *(const short8*)(ldsB + h * 2048 + (wcol * 32 + n * 16 + fr) * 32 + fo);
#pragma unroll
            for (int m = 0; m < 4; ++m) {
                short8 a = *(const short8*)(ldsA + h * 4096 + (wrow * 64 + m * 16 + fr) * 32 + fo);
#pragma unroll
                for (int n = 0; n < 2; ++n)
                    acc[m][n] = __builtin_amdgcn_mfma_f32_16x16x32_bf16(a, bfr[n], acc[m][n], 0, 0, 0);
            }
        }
        __syncthreads();
    }

    // epilogue: C layout col=lane&15, row=(lane>>4)*4+r   [m89/m91]
#pragma unroll
    for (int m = 0; m < 4; ++m) {
        int row_g = rowStart + wrow * 64 + m * 16 + (lane >> 4) * 4;
#pragma unroll
        for (int n = 0; n < 2; ++n) {
            int col_g = colStart + wcol * 32 + n * 16 + (lane & 15);
            float bb = bias[col_g];
#pragma unroll
            for (int r = 0; r < 4; ++r)
                Hbuf[(size_t)(row_g + r) * C_OUT + col_g] = acc[m][n][r] + bb;
        }
    }
}

// ---------- kernel 3: F1[n][h], F2[n][h], and Hb (bf16 copy of Hbuf)
__global__ void k_f12(const float* __restrict__ Hbuf, const float* __restrict__ v0,
                      const float* __restrict__ v1, float* __restrict__ F1,
                      float* __restrict__ F2, unsigned short* __restrict__ Hb) {
    int n = blockIdx.x;
    int t = threadIdx.x;
    int head = t >> 6, lane = t & 63;
    const float* hrow = Hbuf + (size_t)n * C_OUT + head * D_HEAD;
    float h0 = hrow[lane], h1 = hrow[lane + 64];
    unsigned short* hb = Hb + (size_t)n * C_OUT + head * D_HEAD;
    hb[lane]      = f2bf(h0);
    hb[lane + 64] = f2bf(h1);
    const float* v0h = v0 + head * D_HEAD;
    const float* v1h = v1 + head * D_HEAD;
    float s1 = h0 * v0h[lane] + h1 * v0h[lane + 64];
    float s2 = h0 * v1h[lane] + h1 * v1h[lane + 64];
#pragma unroll
    for (int off = 32; off; off >>= 1) {
        s1 += __shfl_xor(s1, off);
        s2 += __shfl_xor(s2, off);
    }
    if (lane == 0) {
        F1[n * 4 + head] = s1;
        F2[n * 4 + head] = s2;
    }
}

// ---------- kernel 4: per-row sparse softmax + PV
#define CHUNK 512
__global__ void k_attn(const float* __restrict__ adj, const unsigned short* __restrict__ Hb,
                       const float* __restrict__ F1, const float* __restrict__ F2,
                       float* __restrict__ Out) {
    __shared__ unsigned short idxs[N_NODES];        // 8 KB (worst-case-proof)
    __shared__ float evals[CHUNK * 4];              // 8 KB
    __shared__ float partial[4][C_OUT];             // 8 KB
    __shared__ int   wtot[4];
    __shared__ float red[16];

    const int i    = blockIdx.x;
    const int t    = threadIdx.x;
    const int lane = t & 63;
    const int wid  = t >> 6;
    const int headl = lane >> 4;    // head of this lane's 8-col PV slice

    float4 f1v = *(const float4*)(F1 + i * 4);

    // ---- phase 1: deterministic compaction of nonzero columns
    const float4* arow = (const float4*)(adj + (size_t)i * N_NODES);
    float4 av[4];
    int cnt = 0;
#pragma unroll
    for (int r = 0; r < 4; ++r) {
        av[r] = arow[r * 256 + t];
        cnt += (av[r].x != 0.f) + (av[r].y != 0.f) + (av[r].z != 0.f) + (av[r].w != 0.f);
    }
    int v = cnt;
#pragma unroll
    for (int off = 1; off < 64; off <<= 1) {
        int u = __shfl_up(v, off);
        if (lane >= off) v += u;
    }
    if (lane == 63) wtot[wid] = v;
    __syncthreads();
    int wpre = 0, nnz = 0;
#pragma unroll
    for (int w = 0; w < 4; ++w) {
        int tw = wtot[w];
        if (w < wid) wpre += tw;
        nnz += tw;
    }
    int off = wpre + v - cnt;
#pragma unroll
    for (int r = 0; r < 4; ++r) {
        int j0 = (r * 256 + t) * 4;
        if (av[r].x != 0.f) idxs[off++] = (unsigned short)j0;
        if (av[r].y != 0.f) idxs[off++] = (unsigned short)(j0 + 1);
        if (av[r].z != 0.f) idxs[off++] = (unsigned short)(j0 + 2);
        if (av[r].w != 0.f) idxs[off++] = (unsigned short)(j0 + 3);
    }
    __syncthreads();

    // ---- phase 2: per-head row max over live entries
    float mx[4] = {-1e30f, -1e30f, -1e30f, -1e30f};
    for (int jj = t; jj < nnz; jj += 256) {
        int j = idxs[jj];
        float4 f2v = *(const float4*)(F2 + j * 4);
        float s0 = f1v.x + f2v.x, s1 = f1v.y + f2v.y;
        float s2 = f1v.z + f2v.z, s3 = f1v.w + f2v.w;
        if (s0 != 0.f) mx[0] = fmaxf(mx[0], sigv(s0));
        if (s1 != 0.f) mx[1] = fmaxf(mx[1], sigv(s1));
        if (s2 != 0.f) mx[2] = fmaxf(mx[2], sigv(s2));
        if (s3 != 0.f) mx[3] = fmaxf(mx[3], sigv(s3));
    }
#pragma unroll
    for (int h = 0; h < 4; ++h)
#pragma unroll
        for (int o2 = 32; o2; o2 >>= 1) mx[h] = fmaxf(mx[h], __shfl_xor(mx[h], o2));
    if (lane == 0) {
        red[wid * 4 + 0] = mx[0]; red[wid * 4 + 1] = mx[1];
        red[wid * 4 + 2] = mx[2]; red[wid * 4 + 3] = mx[3];
    }
    __syncthreads();
    float rowmax[4];
#pragma unroll
    for (int h = 0; h < 4; ++h)
        rowmax[h] = fmaxf(fmaxf(red[0 + h], red[4 + h]), fmaxf(red[8 + h], red[12 + h]));
    __syncthreads();   // red reused below

    // ---- phase 3: exp + denom + warp-parallel PV
    float acc[8];
#pragma unroll
    for (int k = 0; k < 8; ++k) acc[k] = 0.f;
    float dpart[4] = {0.f, 0.f, 0.f, 0.f};

    for (int base = 0; base < nnz; base += CHUNK) {
        int m = min(CHUNK, nnz - base);
        // eval compute: threads t, t+256 entries
        for (int e0i = t; e0i < m; e0i += 256) {
            int j = idxs[base + e0i];
            float4 f2v = *(const float4*)(F2 + j * 4);
            float s0 = f1v.x + f2v.x, s1 = f1v.y + f2v.y;
            float s2 = f1v.z + f2v.z, s3 = f1v.w + f2v.w;
            float e0 = (s0 != 0.f) ? __expf(sigv(s0) - rowmax[0]) : 0.f;
            float e1 = (s1 != 0.f) ? __expf(sigv(s1) - rowmax[1]) : 0.f;
            float e2 = (s2 != 0.f) ? __expf(sigv(s2) - rowmax[2]) : 0.f;
            float e3 = (s3 != 0.f) ? __expf(sigv(s3) - rowmax[3]) : 0.f;
            evals[e0i * 4 + 0] = e0; evals[e0i * 4 + 1] = e1;
            evals[e0i * 4 + 2] = e2; evals[e0i * 4 + 3] = e3;
            dpart[0] += e0; dpart[1] += e1; dpart[2] += e2; dpart[3] += e3;
        }
        __syncthreads();
        // PV: warp wid handles entries wid, wid+4, ... each lane = 8 bf16 cols
        const unsigned short* __restrict__ hp = Hb + lane * 8;
#pragma unroll 2
        for (int jj = wid; jj < m; jj += 4) {
            int j = idxs[base + jj];
            float e = evals[jj * 4 + headl];
            u16x8 hv = *(const u16x8*)(hp + (size_t)j * C_OUT);
#pragma unroll
            for (int k = 0; k < 8; ++k) acc[k] += e * bf2f(hv[k]);
        }
        __syncthreads();   // evals reused next chunk
    }

    // ---- cross-warp PV reduce
#pragma unroll
    for (int k = 0; k < 4; ++k) partial[wid][lane * 8 + k] = acc[k];
#pragma unroll
    for (int k = 4; k < 8; ++k) partial[wid][lane * 8 + k] = acc[k];
    // ---- denom reduce
#pragma unroll
    for (int h = 0; h < 4; ++h)
#pragma unroll
        for (int o2 = 32; o2; o2 >>= 1) dpart[h] += __shfl_xor(dpart[h], o2);
    if (lane == 0) {
        red[wid * 4 + 0] = dpart[0]; red[wid * 4 + 1] = dpart[1];
        red[wid * 4 + 2] = dpart[2]; red[wid * 4 + 3] = dpart[3];
    }
    __syncthreads();
    int head = t >> 6;   // head of this thread's 2 output cols
    float dn = red[0 + head] + red[4 + head] + red[8 + head] + red[12 + head];
    int c = 2 * t;
    float s0 = partial[0][c] + partial[1][c] + partial[2][c] + partial[3][c];
    float s1 = partial[0][c + 1] + partial[1][c + 1] + partial[2][c + 1] + partial[3][c + 1];
    float2 o;
    if (dn > 0.f) {
        float inv = 1.f / fmaxf(dn, 1e-30f);
        o.x = s0 * inv;
        o.y = s1 * inv;
    } else {
        o.x = 0.f; o.y = 0.f;
    }
    *(float2*)(Out + (size_t)i * C_OUT + c) = o;
}

// ---------- launch
extern "C" void kernel_launch(void* const* d_in, const int* in_sizes, int n_in,
                              void* d_out, int out_size, void* d_ws, size_t ws_size,
                              hipStream_t stream) {
    const float* X   = (const float*)d_in[0];
    const float* adj = (const float*)d_in[1];
    const float* W   = (const float*)d_in[2];
    const float* b   = (const float*)d_in[3];
    const float* v0  = (const float*)d_in[4];
    const float* v1  = (const float*)d_in[5];
    float* out = (float*)d_out;

    char* ws = (char*)d_ws;
    float*          Hbuf = (float*)ws;                                          // 8 MB
    unsigned short* Wt   = (unsigned short*)(ws + (size_t)8 * 1024 * 1024);     // 1 MB
    unsigned short* Xb   = (unsigned short*)(ws + (size_t)9 * 1024 * 1024);     // 8 MB
    unsigned short* Hb   = Xb;   // alias: Xb dead after k_gemm; Hb written by k_f12 (4 MB)
    float*          F1   = (float*)(ws + (size_t)17 * 1024 * 1024);             // 64 KB
    float*          F2   = F1 + N_NODES * 4;                                    // 64 KB

    k_xb<<<2048, 256, 0, stream>>>(X, Xb);
    k_wt<<<512, 256, 0, stream>>>(W, Wt);
    k_gemm<<<256, 256, 0, stream>>>(Xb, Wt, b, Hbuf);
    k_f12<<<N_NODES, 256, 0, stream>>>(Hbuf, v0, v1, F1, F2, Hb);
    k_attn<<<N_NODES, 256, 0, stream>>>(adj, Hb, F1, F2, out);
}